// Round 1
// baseline (138.055 us; speedup 1.0000x reference)
//
#include <hip/hip_runtime.h>
#include <hip/hip_bf16.h>

// Net_27358941675610: the 50-step scan collapses to its fixed point:
//   R   = 0.35*sigmoid((6/7)*(psp^T @ W_h^T + b_h))            [4096,2048]
//   out = 0.35*sigmoid(0.75*(R @ W_o^T + b_o) + 0.125*label)   [4096,512]
// Inputs fp32, output fp32. Internal: bf16 MFMA, fp32 acc.
// R16: GEMM1 rebuilt as 256x128-tile, 8-wave, counted-vmcnt pipeline
// (T3/T4 minimum recipe, learn_hip m218): A 3-deep LDS (staged t+2),
// B 2-deep (staged t+1), one raw s_barrier per K-tile, s_waitcnt vmcnt(4)
// steady-state (never 0 mid-loop), setprio(1) around MFMA quad (T5).
// Fragment math / swizzle / epilogue identical to R13-proven code.
// GEMM2: mfma_16x16x32, 32x64 tile, 4 waves of 16x32, grid 1024 (R10-proven).

typedef __bf16 bf16_t;
typedef __bf16 bf16x8 __attribute__((ext_vector_type(8)));
typedef __bf16 bf16x4v __attribute__((ext_vector_type(4)));
typedef float f32x4 __attribute__((ext_vector_type(4)));
typedef float f32x16 __attribute__((ext_vector_type(16)));

#define GLD_TO_LDS16(gp, lp)                                            \
  __builtin_amdgcn_global_load_lds(                                     \
      (__attribute__((address_space(1))) void*)(void*)(gp),             \
      (__attribute__((address_space(3))) void*)(lp), 16, 0, 0)

// ---- prep: psp transpose+cvt AND both weight cvts, one kernel ------------
__global__ __launch_bounds__(256) void prep(
    const float* __restrict__ psp, bf16_t* __restrict__ pspT,
    const float4* __restrict__ w1, bf16x4v* __restrict__ o1, int n1,
    const float4* __restrict__ w2, bf16x4v* __restrict__ o2, int n2) {
  __shared__ float tile[64][65];
  const int tid = threadIdx.x;
  const int b = blockIdx.x;
  const int c0 = (b & 63) * 64;   // batch dim
  const int r0 = (b >> 6) * 64;   // in dim
  const int tx = tid & 63;
  const int ty = tid >> 6;
#pragma unroll
  for (int i = 0; i < 16; ++i) {
    const int r = ty + i * 4;
    tile[r][tx] = psp[(size_t)(r0 + r) * 4096 + c0 + tx];
  }
  const int base = b * 768 + tid;
#pragma unroll
  for (int i = 0; i < 3; ++i) {
    const int idx = base + i * 256;
    const float4 v = (idx < n1) ? w1[idx] : w2[idx - n1];
    bf16x4v o;
    o.x = (bf16_t)v.x; o.y = (bf16_t)v.y; o.z = (bf16_t)v.z; o.w = (bf16_t)v.w;
    if (idx < n1) o1[idx] = o;
    else if (idx - n1 < n2) o2[idx - n1] = o;
  }
  __syncthreads();
#pragma unroll
  for (int i = 0; i < 16; ++i) {
    const int r = ty + i * 4;
    pspT[(size_t)(c0 + r) * 1024 + r0 + tx] = (bf16_t)tile[tx][r];
  }
}

// ---- GEMM1: R(bf16) = 0.35*sigmoid(6/7*(A @ Bt^T + bias)) ----------------
// mfma_f32_32x32x16_bf16. 256x128 tile, 8 waves of 64x64 (2x2 of 32x32),
// BK=64. Pipelined: sA 3-deep (96KB), sB 2-deep (32KB) = 128KB LDS,
// grid (16,16)=256 -> 1 block/CU. Counted vmcnt, 1 barrier per K-tile.
__global__ __launch_bounds__(512, 2) void gemm1_nt(
    const bf16_t* __restrict__ A, const bf16_t* __restrict__ Bt,
    const float* __restrict__ bias, bf16_t* __restrict__ C,
    int M, int N, int K) {
  constexpr int BK = 64;
  __shared__ __align__(16) bf16_t sA[3][256 * BK];  // 96 KB
  __shared__ __align__(16) bf16_t sB[2][128 * BK];  // 32 KB

  const int tid = threadIdx.x;
  const int wave = tid >> 6;  // 0..7
  const int lane = tid & 63;
  const int bm = blockIdx.x * 256;
  const int bn = blockIdx.y * 128;
  const int wm = (wave & 3) * 64;   // 4 M-positions
  const int wn = (wave >> 2) * 64;  // 2 N-positions

  f32x16 acc[2][2] = {};

  const int srow8 = lane >> 3;
  const int gseg = (lane & 7) ^ srow8;  // pre-swizzled global k-segment
  const bf16_t* Ag = A + (size_t)(bm + wave * 32 + srow8) * K + gseg * 8;
  const bf16_t* Bg = Bt + (size_t)(bn + wave * 16 + srow8) * K + gseg * 8;
  const int dstA = wave * 2048;  // elements within one A buffer
  const int dstB = wave * 1024;  // elements within one B buffer

  const int col = lane & 31;
  const int g = lane >> 5;
  const int NT = K / BK;  // 16

  // stage tile t: A -> sA[t%3] (4 gld_lds), B -> sB[t%2] (2 gld_lds)
#define STAGE_A(t)                                                   \
  do {                                                               \
    bf16_t* d_ = &sA[(t) % 3][dstA];                                 \
    const bf16_t* s_ = Ag + (size_t)(t) * BK;                        \
    _Pragma("unroll") for (int c_ = 0; c_ < 4; ++c_)                 \
        GLD_TO_LDS16(s_ + (size_t)(c_ * 8) * K, d_ + c_ * 512);      \
  } while (0)
#define STAGE_B(t)                                                   \
  do {                                                               \
    bf16_t* d_ = &sB[(t) % 2][dstB];                                 \
    const bf16_t* s_ = Bg + (size_t)(t) * BK;                        \
    _Pragma("unroll") for (int c_ = 0; c_ < 2; ++c_)                 \
        GLD_TO_LDS16(s_ + (size_t)(c_ * 8) * K, d_ + c_ * 512);      \
  } while (0)

  // prologue: in-flight order [A0(4) B0(2) A1(4)]; vmcnt(4) drains A0,B0.
  STAGE_A(0);
  STAGE_B(0);
  STAGE_A(1);
  asm volatile("s_waitcnt vmcnt(4)" ::: "memory");
  __builtin_amdgcn_s_barrier();
  __builtin_amdgcn_sched_barrier(0);

  for (int t = 0; t < NT; ++t) {
    // issue next loads FIRST: B(t+1) then A(t+2); end-of-tile in-flight is
    // [A(t+1) B(t+1) A(t+2)] -> vmcnt(4) drains exactly A(t+1)+B(t+1).
    if (t + 1 < NT) STAGE_B(t + 1);
    if (t + 2 < NT) STAGE_A(t + 2);

    const bf16_t* a_ = sA[t % 3];
    const bf16_t* b_ = sB[t % 2];
#pragma unroll
    for (int ks = 0; ks < 4; ++ks) {
      const int q = ks * 2 + g;
      bf16x8 av[2], bv[2];
#pragma unroll
      for (int i = 0; i < 2; ++i) {
        const int rr = wm + i * 32 + col;
        av[i] = *(const bf16x8*)(a_ + rr * BK + ((q ^ (rr & 7)) * 8));
      }
#pragma unroll
      for (int j = 0; j < 2; ++j) {
        const int rr = wn + j * 32 + col;
        bv[j] = *(const bf16x8*)(b_ + rr * BK + ((q ^ (rr & 7)) * 8));
      }
      __builtin_amdgcn_s_setprio(1);
#pragma unroll
      for (int i = 0; i < 2; ++i)
#pragma unroll
        for (int j = 0; j < 2; ++j)
          acc[i][j] = __builtin_amdgcn_mfma_f32_32x32x16_bf16(
              av[i], bv[j], acc[i][j], 0, 0, 0);
      __builtin_amdgcn_s_setprio(0);
    }

    if (t + 1 < NT) {
      if (t + 2 < NT)
        asm volatile("s_waitcnt vmcnt(4) lgkmcnt(0)" ::: "memory");
      else  // tail: only A(NT-1)+B(NT-1) remain in flight
        asm volatile("s_waitcnt vmcnt(0) lgkmcnt(0)" ::: "memory");
      __builtin_amdgcn_s_barrier();
      __builtin_amdgcn_sched_barrier(0);
    }
  }
#undef STAGE_A
#undef STAGE_B

  // epilogue: col = lane&31, row = (r&3) + 8*(r>>2) + 4*(lane>>5) [m74/m101]
  const int rbase = 4 * g;
#pragma unroll
  for (int j = 0; j < 2; ++j) {
    const int gn = bn + wn + j * 32 + col;
    const float bj = bias[gn];
#pragma unroll
    for (int i = 0; i < 2; ++i) {
#pragma unroll
      for (int r = 0; r < 16; ++r) {
        const int gm = bm + wm + i * 32 + (r & 3) + 8 * (r >> 2) + rbase;
        const float z = 0.8571428571428571f * (acc[i][j][r] + bj);
        C[(size_t)gm * N + gn] = (bf16_t)(0.35f / (1.0f + __expf(-z)));
      }
    }
  }
}

// ---- GEMM2: out(fp32) = 0.35*sigmoid(0.75*(R @ Wo^T + b_o) + 0.125*lbl) --
// R10 verbatim (proven). 32x64 tile, 4 waves of 16x32, BK=64, grid 1024.
__global__ __launch_bounds__(256, 4) void gemm2_nt(
    const bf16_t* __restrict__ A, const bf16_t* __restrict__ Bt,
    const float* __restrict__ bias, const float* __restrict__ lbl,
    float* __restrict__ out, int M, int N, int K) {
  constexpr int BK = 64;
  __shared__ __align__(16) bf16_t sA[32 * BK];  // 4 KB
  __shared__ __align__(16) bf16_t sB[64 * BK];  // 8 KB

  const int tid = threadIdx.x;
  const int wave = tid >> 6;
  const int lane = tid & 63;
  const int bm = blockIdx.x * 32;
  const int bn = blockIdx.y * 64;
  const int wm = (wave & 1) * 16;
  const int wn = (wave >> 1) * 32;

  f32x4 acc[2] = {};

  const int srow8 = lane >> 3;
  const int gseg = (lane & 7) ^ srow8;
  const bf16_t* Ag = A + (size_t)(bm + wave * 8 + srow8) * K + gseg * 8;
  const bf16_t* Bg = Bt + (size_t)(bn + wave * 16 + srow8) * K + gseg * 8;
  const int dstA = wave * 512;
  const int dstB = wave * 1024;

  const int fr = lane & 15;
  const int qh = lane >> 4;

  for (int k0 = 0; k0 < K; k0 += BK) {
    GLD_TO_LDS16(Ag + k0, sA + dstA);
#pragma unroll
    for (int c = 0; c < 2; ++c)
      GLD_TO_LDS16(Bg + (size_t)(c * 8) * K + k0, sB + dstB + c * 512);
    __syncthreads();

#pragma unroll
    for (int ks = 0; ks < 2; ++ks) {
      const int q = ks * 4 + qh;
      const int ra = wm + fr;
      const bf16x8 av = *(const bf16x8*)(sA + ra * BK + ((q ^ (ra & 7)) * 8));
      bf16x8 bv[2];
#pragma unroll
      for (int j = 0; j < 2; ++j) {
        const int rr = wn + j * 16 + fr;
        bv[j] = *(const bf16x8*)(sB + rr * BK + ((q ^ (rr & 7)) * 8));
      }
#pragma unroll
      for (int j = 0; j < 2; ++j)
        acc[j] = __builtin_amdgcn_mfma_f32_16x16x32_bf16(av, bv[j], acc[j],
                                                         0, 0, 0);
    }
    __syncthreads();
  }

  const int cm0 = (lane >> 4) * 4;
#pragma unroll
  for (int j = 0; j < 2; ++j) {
    const int gn = bn + wn + j * 16 + fr;
    const float bj = bias[gn];
#pragma unroll
    for (int r = 0; r < 4; ++r) {
      const int gm = bm + wm + cm0 + r;
      const float z =
          0.75f * (acc[j][r] + bj) + 0.125f * lbl[(size_t)gm * N + gn];
      out[(size_t)gm * N + gn] = 0.35f / (1.0f + __expf(-z));
    }
  }
}

extern "C" void kernel_launch(void* const* d_in, const int* in_sizes, int n_in,
                              void* d_out, int out_size, void* d_ws, size_t ws_size,
                              hipStream_t stream) {
  constexpr int IN = 1024, HID = 2048, OUT = 512, B = 4096;
  const float* psp = (const float*)d_in[0];   // [IN, B]
  const float* lbl = (const float*)d_in[1];   // [B, OUT]
  const float* W_h = (const float*)d_in[2];   // [HID, IN]
  const float* b_h = (const float*)d_in[3];   // [HID]
  const float* W_o = (const float*)d_in[4];   // [OUT, HID]
  const float* b_o = (const float*)d_in[5];   // [OUT]
  float* out = (float*)d_out;                 // [B, OUT] fp32

  bf16_t* Whb = (bf16_t*)d_ws;                 // [HID, IN]  4 MB
  bf16_t* Wob = Whb + (size_t)HID * IN;        // [OUT, HID] 2 MB
  bf16_t* pspT = Wob + (size_t)OUT * HID;      // [B, IN]    8 MB
  bf16_t* Rm = pspT + (size_t)B * IN;          // [B, HID]  16 MB

  prep<<<1024, 256, 0, stream>>>(
      psp, pspT, (const float4*)W_h, (bf16x4v*)Whb, HID * IN / 4,
      (const float4*)W_o, (bf16x4v*)Wob, OUT * HID / 4);
  gemm1_nt<<<dim3(B / 256, HID / 128), 512, 0, stream>>>(
      pspT, Whb, b_h, Rm, B, HID, IN);
  gemm2_nt<<<dim3(B / 32, OUT / 64), 256, 0, stream>>>(
      Rm, Wob, b_o, lbl, out, B, OUT, HID);
}

// Round 2
// 130.773 us; speedup vs baseline: 1.0557x; 1.0557x over previous
//
#include <hip/hip_runtime.h>
#include <hip/hip_bf16.h>

// Net_27358941675610: the 50-step scan collapses to its fixed point:
//   R   = 0.35*sigmoid((6/7)*(psp^T @ W_h^T + b_h))            [4096,2048]
//   out = 0.35*sigmoid(0.75*(R @ W_o^T + b_o) + 0.125*label)   [4096,512]
// Inputs fp32, output fp32. Internal: bf16 MFMA, fp32 acc.
// R17: gemm1 occupancy fix. R16's counted-vmcnt 1-block/CU pipeline hit the
// m196 failure mode (coarse phase-split without fine interleave) and the
// m102 1-blk/CU point (~340 TF). Revert to the R13-proven m97-class loop
// but with 128x64 tile / grid 1024 -> 4 blocks/CU (24KB LDS, ~80 VGPR),
// exploiting the m102 occupancy curve (1/CU=320 TF -> 4/CU=833 TF).
// GEMM2: mfma_16x16x32, 32x64 tile, 4 waves of 16x32, grid 1024 (R10-proven).

typedef __bf16 bf16_t;
typedef __bf16 bf16x8 __attribute__((ext_vector_type(8)));
typedef __bf16 bf16x4v __attribute__((ext_vector_type(4)));
typedef float f32x4 __attribute__((ext_vector_type(4)));
typedef float f32x16 __attribute__((ext_vector_type(16)));

#define GLD_TO_LDS16(gp, lp)                                            \
  __builtin_amdgcn_global_load_lds(                                     \
      (__attribute__((address_space(1))) void*)(void*)(gp),             \
      (__attribute__((address_space(3))) void*)(lp), 16, 0, 0)

// ---- prep: psp transpose+cvt AND both weight cvts, one kernel ------------
__global__ __launch_bounds__(256) void prep(
    const float* __restrict__ psp, bf16_t* __restrict__ pspT,
    const float4* __restrict__ w1, bf16x4v* __restrict__ o1, int n1,
    const float4* __restrict__ w2, bf16x4v* __restrict__ o2, int n2) {
  __shared__ float tile[64][65];
  const int tid = threadIdx.x;
  const int b = blockIdx.x;
  const int c0 = (b & 63) * 64;   // batch dim
  const int r0 = (b >> 6) * 64;   // in dim
  const int tx = tid & 63;
  const int ty = tid >> 6;
#pragma unroll
  for (int i = 0; i < 16; ++i) {
    const int r = ty + i * 4;
    tile[r][tx] = psp[(size_t)(r0 + r) * 4096 + c0 + tx];
  }
  const int base = b * 768 + tid;
#pragma unroll
  for (int i = 0; i < 3; ++i) {
    const int idx = base + i * 256;
    const float4 v = (idx < n1) ? w1[idx] : w2[idx - n1];
    bf16x4v o;
    o.x = (bf16_t)v.x; o.y = (bf16_t)v.y; o.z = (bf16_t)v.z; o.w = (bf16_t)v.w;
    if (idx < n1) o1[idx] = o;
    else if (idx - n1 < n2) o2[idx - n1] = o;
  }
  __syncthreads();
#pragma unroll
  for (int i = 0; i < 16; ++i) {
    const int r = ty + i * 4;
    pspT[(size_t)(c0 + r) * 1024 + r0 + tx] = (bf16_t)tile[tx][r];
  }
}

// ---- GEMM1: R(bf16) = 0.35*sigmoid(6/7*(A @ Bt^T + bias)) ----------------
// mfma_f32_32x32x16_bf16. 128x64 tile, 4 waves of 64x32 (2x1 of 32x32),
// BK=64, single-buffer LDS 24KB, grid (32,32)=1024 -> 4 blocks/CU.
__global__ __launch_bounds__(256, 4) void gemm1_nt(
    const bf16_t* __restrict__ A, const bf16_t* __restrict__ Bt,
    const float* __restrict__ bias, bf16_t* __restrict__ C,
    int M, int N, int K) {
  constexpr int BK = 64;
  __shared__ __align__(16) bf16_t sA[128 * BK];  // 16 KB
  __shared__ __align__(16) bf16_t sB[64 * BK];   //  8 KB

  const int tid = threadIdx.x;
  const int wave = tid >> 6;  // 0..3
  const int lane = tid & 63;
  const int bm = blockIdx.x * 128;
  const int bn = blockIdx.y * 64;
  const int wm = (wave & 1) * 64;   // 2 M-positions
  const int wn = (wave >> 1) * 32;  // 2 N-positions

  f32x16 acc[2] = {};

  const int srow8 = lane >> 3;
  const int gseg = (lane & 7) ^ srow8;  // pre-swizzled global k-segment
  const bf16_t* Ag = A + (size_t)(bm + wave * 32 + srow8) * K + gseg * 8;
  const bf16_t* Bg = Bt + (size_t)(bn + wave * 16 + srow8) * K + gseg * 8;
  const int dstA = wave * 2048;  // wave*32 rows
  const int dstB = wave * 1024;  // wave*16 rows

  const int col = lane & 31;
  const int g = lane >> 5;

  for (int k0 = 0; k0 < K; k0 += BK) {
#pragma unroll
    for (int c = 0; c < 4; ++c)
      GLD_TO_LDS16(Ag + (size_t)(c * 8) * K + k0, sA + dstA + c * 512);
#pragma unroll
    for (int c = 0; c < 2; ++c)
      GLD_TO_LDS16(Bg + (size_t)(c * 8) * K + k0, sB + dstB + c * 512);
    __syncthreads();

#pragma unroll
    for (int ks = 0; ks < 4; ++ks) {
      const int q = ks * 2 + g;
      bf16x8 av[2], bv;
#pragma unroll
      for (int i = 0; i < 2; ++i) {
        const int rr = wm + i * 32 + col;
        av[i] = *(const bf16x8*)(sA + rr * BK + ((q ^ (rr & 7)) * 8));
      }
      {
        const int rr = wn + col;
        bv = *(const bf16x8*)(sB + rr * BK + ((q ^ (rr & 7)) * 8));
      }
#pragma unroll
      for (int i = 0; i < 2; ++i)
        acc[i] = __builtin_amdgcn_mfma_f32_32x32x16_bf16(av[i], bv, acc[i],
                                                         0, 0, 0);
    }
    __syncthreads();
  }

  // epilogue: col = lane&31, row = (r&3) + 8*(r>>2) + 4*(lane>>5) [m74/m101]
  const int rbase = 4 * g;
  const int gn = bn + wn + col;
  const float bj = bias[gn];
#pragma unroll
  for (int i = 0; i < 2; ++i) {
#pragma unroll
    for (int r = 0; r < 16; ++r) {
      const int gm = bm + wm + i * 32 + (r & 3) + 8 * (r >> 2) + rbase;
      const float z = 0.8571428571428571f * (acc[i][r] + bj);
      C[(size_t)gm * N + gn] = (bf16_t)(0.35f / (1.0f + __expf(-z)));
    }
  }
}

// ---- GEMM2: out(fp32) = 0.35*sigmoid(0.75*(R @ Wo^T + b_o) + 0.125*lbl) --
// R10 verbatim (proven). 32x64 tile, 4 waves of 16x32, BK=64, grid 1024.
__global__ __launch_bounds__(256, 4) void gemm2_nt(
    const bf16_t* __restrict__ A, const bf16_t* __restrict__ Bt,
    const float* __restrict__ bias, const float* __restrict__ lbl,
    float* __restrict__ out, int M, int N, int K) {
  constexpr int BK = 64;
  __shared__ __align__(16) bf16_t sA[32 * BK];  // 4 KB
  __shared__ __align__(16) bf16_t sB[64 * BK];  // 8 KB

  const int tid = threadIdx.x;
  const int wave = tid >> 6;
  const int lane = tid & 63;
  const int bm = blockIdx.x * 32;
  const int bn = blockIdx.y * 64;
  const int wm = (wave & 1) * 16;
  const int wn = (wave >> 1) * 32;

  f32x4 acc[2] = {};

  const int srow8 = lane >> 3;
  const int gseg = (lane & 7) ^ srow8;
  const bf16_t* Ag = A + (size_t)(bm + wave * 8 + srow8) * K + gseg * 8;
  const bf16_t* Bg = Bt + (size_t)(bn + wave * 16 + srow8) * K + gseg * 8;
  const int dstA = wave * 512;
  const int dstB = wave * 1024;

  const int fr = lane & 15;
  const int qh = lane >> 4;

  for (int k0 = 0; k0 < K; k0 += BK) {
    GLD_TO_LDS16(Ag + k0, sA + dstA);
#pragma unroll
    for (int c = 0; c < 2; ++c)
      GLD_TO_LDS16(Bg + (size_t)(c * 8) * K + k0, sB + dstB + c * 512);
    __syncthreads();

#pragma unroll
    for (int ks = 0; ks < 2; ++ks) {
      const int q = ks * 4 + qh;
      const int ra = wm + fr;
      const bf16x8 av = *(const bf16x8*)(sA + ra * BK + ((q ^ (ra & 7)) * 8));
      bf16x8 bv[2];
#pragma unroll
      for (int j = 0; j < 2; ++j) {
        const int rr = wn + j * 16 + fr;
        bv[j] = *(const bf16x8*)(sB + rr * BK + ((q ^ (rr & 7)) * 8));
      }
#pragma unroll
      for (int j = 0; j < 2; ++j)
        acc[j] = __builtin_amdgcn_mfma_f32_16x16x32_bf16(av, bv[j], acc[j],
                                                         0, 0, 0);
    }
    __syncthreads();
  }

  const int cm0 = (lane >> 4) * 4;
#pragma unroll
  for (int j = 0; j < 2; ++j) {
    const int gn = bn + wn + j * 16 + fr;
    const float bj = bias[gn];
#pragma unroll
    for (int r = 0; r < 4; ++r) {
      const int gm = bm + wm + cm0 + r;
      const float z =
          0.75f * (acc[j][r] + bj) + 0.125f * lbl[(size_t)gm * N + gn];
      out[(size_t)gm * N + gn] = 0.35f / (1.0f + __expf(-z));
    }
  }
}

extern "C" void kernel_launch(void* const* d_in, const int* in_sizes, int n_in,
                              void* d_out, int out_size, void* d_ws, size_t ws_size,
                              hipStream_t stream) {
  constexpr int IN = 1024, HID = 2048, OUT = 512, B = 4096;
  const float* psp = (const float*)d_in[0];   // [IN, B]
  const float* lbl = (const float*)d_in[1];   // [B, OUT]
  const float* W_h = (const float*)d_in[2];   // [HID, IN]
  const float* b_h = (const float*)d_in[3];   // [HID]
  const float* W_o = (const float*)d_in[4];   // [OUT, HID]
  const float* b_o = (const float*)d_in[5];   // [OUT]
  float* out = (float*)d_out;                 // [B, OUT] fp32

  bf16_t* Whb = (bf16_t*)d_ws;                 // [HID, IN]  4 MB
  bf16_t* Wob = Whb + (size_t)HID * IN;        // [OUT, HID] 2 MB
  bf16_t* pspT = Wob + (size_t)OUT * HID;      // [B, IN]    8 MB
  bf16_t* Rm = pspT + (size_t)B * IN;          // [B, HID]  16 MB

  prep<<<1024, 256, 0, stream>>>(
      psp, pspT, (const float4*)W_h, (bf16x4v*)Whb, HID * IN / 4,
      (const float4*)W_o, (bf16x4v*)Wob, OUT * HID / 4);
  gemm1_nt<<<dim3(B / 128, HID / 64), 256, 0, stream>>>(
      pspT, Whb, b_h, Rm, B, HID, IN);
  gemm2_nt<<<dim3(B / 32, OUT / 64), 256, 0, stream>>>(
      Rm, Wob, b_o, lbl, out, B, OUT, HID);
}

// Round 3
// 129.340 us; speedup vs baseline: 1.0674x; 1.0111x over previous
//
#include <hip/hip_runtime.h>
#include <hip/hip_bf16.h>

// Net_27358941675610: the 50-step scan collapses to its fixed point:
//   R   = 0.35*sigmoid((6/7)*(psp^T @ W_h^T + b_h))            [4096,2048]
//   out = 0.35*sigmoid(0.75*(R @ W_o^T + b_o) + 0.125*label)   [4096,512]
// Inputs fp32, output fp32. Internal: bf16 MFMA, fp32 acc.
// R18: gemm2 rebuilt. R10's 32x64 tile had 4 MFMA per barrier-epoch vs
// 6 ds_read_b128 (epoch/LDS-bound, ~230 TF). New: 64x64 tile, 4 waves of
// 32x32 via 2x2 frags of 16x16 (reads/MFMA 1.5->1.0), BK=128 as TWO proven
// BK=64 panels (identical staging/swizzle per panel), 16 epochs, grid 512
// -> 2 blk/CU. gemm1 = R17 (128x64, 4 blk/CU, ~420 TF). prep unchanged.

typedef __bf16 bf16_t;
typedef __bf16 bf16x8 __attribute__((ext_vector_type(8)));
typedef __bf16 bf16x4v __attribute__((ext_vector_type(4)));
typedef float f32x4 __attribute__((ext_vector_type(4)));
typedef float f32x16 __attribute__((ext_vector_type(16)));

#define GLD_TO_LDS16(gp, lp)                                            \
  __builtin_amdgcn_global_load_lds(                                     \
      (__attribute__((address_space(1))) void*)(void*)(gp),             \
      (__attribute__((address_space(3))) void*)(lp), 16, 0, 0)

// ---- prep: psp transpose+cvt AND both weight cvts, one kernel ------------
__global__ __launch_bounds__(256) void prep(
    const float* __restrict__ psp, bf16_t* __restrict__ pspT,
    const float4* __restrict__ w1, bf16x4v* __restrict__ o1, int n1,
    const float4* __restrict__ w2, bf16x4v* __restrict__ o2, int n2) {
  __shared__ float tile[64][65];
  const int tid = threadIdx.x;
  const int b = blockIdx.x;
  const int c0 = (b & 63) * 64;   // batch dim
  const int r0 = (b >> 6) * 64;   // in dim
  const int tx = tid & 63;
  const int ty = tid >> 6;
#pragma unroll
  for (int i = 0; i < 16; ++i) {
    const int r = ty + i * 4;
    tile[r][tx] = psp[(size_t)(r0 + r) * 4096 + c0 + tx];
  }
  const int base = b * 768 + tid;
#pragma unroll
  for (int i = 0; i < 3; ++i) {
    const int idx = base + i * 256;
    const float4 v = (idx < n1) ? w1[idx] : w2[idx - n1];
    bf16x4v o;
    o.x = (bf16_t)v.x; o.y = (bf16_t)v.y; o.z = (bf16_t)v.z; o.w = (bf16_t)v.w;
    if (idx < n1) o1[idx] = o;
    else if (idx - n1 < n2) o2[idx - n1] = o;
  }
  __syncthreads();
#pragma unroll
  for (int i = 0; i < 16; ++i) {
    const int r = ty + i * 4;
    pspT[(size_t)(c0 + r) * 1024 + r0 + tx] = (bf16_t)tile[tx][r];
  }
}

// ---- GEMM1: R(bf16) = 0.35*sigmoid(6/7*(A @ Bt^T + bias)) ----------------
// R17-proven. mfma_f32_32x32x16_bf16. 128x64 tile, 4 waves of 64x32,
// BK=64, single-buffer LDS 24KB, grid (32,32)=1024 -> 4 blocks/CU.
__global__ __launch_bounds__(256, 4) void gemm1_nt(
    const bf16_t* __restrict__ A, const bf16_t* __restrict__ Bt,
    const float* __restrict__ bias, bf16_t* __restrict__ C,
    int M, int N, int K) {
  constexpr int BK = 64;
  __shared__ __align__(16) bf16_t sA[128 * BK];  // 16 KB
  __shared__ __align__(16) bf16_t sB[64 * BK];   //  8 KB

  const int tid = threadIdx.x;
  const int wave = tid >> 6;  // 0..3
  const int lane = tid & 63;
  const int bm = blockIdx.x * 128;
  const int bn = blockIdx.y * 64;
  const int wm = (wave & 1) * 64;   // 2 M-positions
  const int wn = (wave >> 1) * 32;  // 2 N-positions

  f32x16 acc[2] = {};

  const int srow8 = lane >> 3;
  const int gseg = (lane & 7) ^ srow8;  // pre-swizzled global k-segment
  const bf16_t* Ag = A + (size_t)(bm + wave * 32 + srow8) * K + gseg * 8;
  const bf16_t* Bg = Bt + (size_t)(bn + wave * 16 + srow8) * K + gseg * 8;
  const int dstA = wave * 2048;  // wave*32 rows
  const int dstB = wave * 1024;  // wave*16 rows

  const int col = lane & 31;
  const int g = lane >> 5;

  for (int k0 = 0; k0 < K; k0 += BK) {
#pragma unroll
    for (int c = 0; c < 4; ++c)
      GLD_TO_LDS16(Ag + (size_t)(c * 8) * K + k0, sA + dstA + c * 512);
#pragma unroll
    for (int c = 0; c < 2; ++c)
      GLD_TO_LDS16(Bg + (size_t)(c * 8) * K + k0, sB + dstB + c * 512);
    __syncthreads();

#pragma unroll
    for (int ks = 0; ks < 4; ++ks) {
      const int q = ks * 2 + g;
      bf16x8 av[2], bv;
#pragma unroll
      for (int i = 0; i < 2; ++i) {
        const int rr = wm + i * 32 + col;
        av[i] = *(const bf16x8*)(sA + rr * BK + ((q ^ (rr & 7)) * 8));
      }
      {
        const int rr = wn + col;
        bv = *(const bf16x8*)(sB + rr * BK + ((q ^ (rr & 7)) * 8));
      }
#pragma unroll
      for (int i = 0; i < 2; ++i)
        acc[i] = __builtin_amdgcn_mfma_f32_32x32x16_bf16(av[i], bv, acc[i],
                                                         0, 0, 0);
    }
    __syncthreads();
  }

  // epilogue: col = lane&31, row = (r&3) + 8*(r>>2) + 4*(lane>>5) [m74/m101]
  const int rbase = 4 * g;
  const int gn = bn + wn + col;
  const float bj = bias[gn];
#pragma unroll
  for (int i = 0; i < 2; ++i) {
#pragma unroll
    for (int r = 0; r < 16; ++r) {
      const int gm = bm + wm + i * 32 + (r & 3) + 8 * (r >> 2) + rbase;
      const float z = 0.8571428571428571f * (acc[i][r] + bj);
      C[(size_t)gm * N + gn] = (bf16_t)(0.35f / (1.0f + __expf(-z)));
    }
  }
}

// ---- GEMM2: out(fp32) = 0.35*sigmoid(0.75*(R @ Wo^T + b_o) + 0.125*lbl) --
// R18: 64x64 tile, 4 waves of 32x32 (2x2 frags of 16x16), BK=128 as two
// proven BK=64 panels. 16 epochs, 16 MFMA/epoch/wave, grid (64,8)=512.
__global__ __launch_bounds__(256, 4) void gemm2_nt(
    const bf16_t* __restrict__ A, const bf16_t* __restrict__ Bt,
    const float* __restrict__ bias, const float* __restrict__ lbl,
    float* __restrict__ out, int M, int N, int K) {
  __shared__ __align__(16) bf16_t sA[2][64 * 64];  // 16 KB (2 K-panels)
  __shared__ __align__(16) bf16_t sB[2][64 * 64];  // 16 KB

  const int tid = threadIdx.x;
  const int wave = tid >> 6;
  const int lane = tid & 63;
  const int bm = blockIdx.x * 64;
  const int bn = blockIdx.y * 64;
  const int wm = (wave & 1) * 32;
  const int wn = (wave >> 1) * 32;

  f32x4 acc[2][2] = {};

  const int srow8 = lane >> 3;
  const int gseg = (lane & 7) ^ srow8;  // pre-swizzled global k-segment
  const bf16_t* Ag = A + (size_t)(bm + wave * 16 + srow8) * K + gseg * 8;
  const bf16_t* Bg = Bt + (size_t)(bn + wave * 16 + srow8) * K + gseg * 8;
  const int dst = wave * 1024;  // 16 rows * 64 elems per wave, per panel

  const int fr = lane & 15;
  const int qh = lane >> 4;

  for (int k0 = 0; k0 < K; k0 += 128) {
#pragma unroll
    for (int p = 0; p < 2; ++p) {
#pragma unroll
      for (int c = 0; c < 2; ++c) {
        GLD_TO_LDS16(Ag + k0 + p * 64 + (size_t)(c * 8) * K,
                     sA[p] + dst + c * 512);
        GLD_TO_LDS16(Bg + k0 + p * 64 + (size_t)(c * 8) * K,
                     sB[p] + dst + c * 512);
      }
    }
    __syncthreads();

#pragma unroll
    for (int ks = 0; ks < 4; ++ks) {
      const int q = ks * 4 + qh;   // granule 0..15 across BK=128
      const int pnl = q >> 3;      // panel (wave-uniform per ks)
      const int q2 = q & 7;        // granule within panel
      bf16x8 av[2], bv[2];
#pragma unroll
      for (int i = 0; i < 2; ++i) {
        const int ra = wm + i * 16 + fr;
        av[i] = *(const bf16x8*)(sA[pnl] + ra * 64 + ((q2 ^ (ra & 7)) * 8));
      }
#pragma unroll
      for (int j = 0; j < 2; ++j) {
        const int rb = wn + j * 16 + fr;
        bv[j] = *(const bf16x8*)(sB[pnl] + rb * 64 + ((q2 ^ (rb & 7)) * 8));
      }
#pragma unroll
      for (int i = 0; i < 2; ++i)
#pragma unroll
        for (int j = 0; j < 2; ++j)
          acc[i][j] = __builtin_amdgcn_mfma_f32_16x16x32_bf16(
              av[i], bv[j], acc[i][j], 0, 0, 0);
    }
    __syncthreads();
  }

  // epilogue: col = lane&15, row = (lane>>4)*4 + reg [m89/m91]
  const int cm0 = qh * 4;
#pragma unroll
  for (int j = 0; j < 2; ++j) {
    const int gn = bn + wn + j * 16 + fr;
    const float bj = bias[gn];
#pragma unroll
    for (int i = 0; i < 2; ++i) {
#pragma unroll
      for (int r = 0; r < 4; ++r) {
        const int gm = bm + wm + i * 16 + cm0 + r;
        const float z =
            0.75f * (acc[i][j][r] + bj) + 0.125f * lbl[(size_t)gm * N + gn];
        out[(size_t)gm * N + gn] = 0.35f / (1.0f + __expf(-z));
      }
    }
  }
}

extern "C" void kernel_launch(void* const* d_in, const int* in_sizes, int n_in,
                              void* d_out, int out_size, void* d_ws, size_t ws_size,
                              hipStream_t stream) {
  constexpr int IN = 1024, HID = 2048, OUT = 512, B = 4096;
  const float* psp = (const float*)d_in[0];   // [IN, B]
  const float* lbl = (const float*)d_in[1];   // [B, OUT]
  const float* W_h = (const float*)d_in[2];   // [HID, IN]
  const float* b_h = (const float*)d_in[3];   // [HID]
  const float* W_o = (const float*)d_in[4];   // [OUT, HID]
  const float* b_o = (const float*)d_in[5];   // [OUT]
  float* out = (float*)d_out;                 // [B, OUT] fp32

  bf16_t* Whb = (bf16_t*)d_ws;                 // [HID, IN]  4 MB
  bf16_t* Wob = Whb + (size_t)HID * IN;        // [OUT, HID] 2 MB
  bf16_t* pspT = Wob + (size_t)OUT * HID;      // [B, IN]    8 MB
  bf16_t* Rm = pspT + (size_t)B * IN;          // [B, HID]  16 MB

  prep<<<1024, 256, 0, stream>>>(
      psp, pspT, (const float4*)W_h, (bf16x4v*)Whb, HID * IN / 4,
      (const float4*)W_o, (bf16x4v*)Wob, OUT * HID / 4);
  gemm1_nt<<<dim3(B / 128, HID / 64), 256, 0, stream>>>(
      pspT, Whb, b_h, Rm, B, HID, IN);
  gemm2_nt<<<dim3(B / 64, OUT / 64), 256, 0, stream>>>(
      Rm, Wob, b_o, lbl, out, B, OUT, HID);
}